// Round 3
// baseline (2260.000 us; speedup 1.0000x reference)
//
#include <hip/hip_runtime.h>
#include <cstddef>
#include <cstdint>

// ---------------------------------------------------------------------------
// SwinTransformerBlock (PoLA attention), B=2, RES=(32,32,16), WS=(8,8,8)
// fp32 in/out; bf16 activations in workspace; fp32 weights.
// NOTE: the reference's  vv.reshape(B_, N, C)  after the depthwise conv is a
// channel SCRAMBLE (no head transpose!): (h,n,d) -> flat = h*16384+n*32+d ->
// (n', c') = (flat/384, flat%384). We replicate that exactly.
// ---------------------------------------------------------------------------
constexpr int DIMC  = 384;
constexpr int HEADS = 12;
constexpr int HD    = 32;
constexpr int NWINP = 512;
constexpr int TOT   = 32768;   // B * 32*32*16
constexpr int QKVW  = 1152;    // k,v,g only (3*384)

using u16 = unsigned short;

__device__ __forceinline__ float bf2f(u16 u) {
    union { uint32_t i; float f; } c; c.i = ((uint32_t)u) << 16; return c.f;
}
__device__ __forceinline__ u16 f2bf(float f) {
    union { float f; uint32_t i; } c; c.f = f;
    uint32_t r = c.i + 0x7fffu + ((c.i >> 16) & 1u);
    return (u16)(r >> 16);
}
__device__ __forceinline__ float relu_pow_f(float x, float p) {
    return (x > 0.f) ? __expf(p * __logf(x)) : 0.f;
}
__device__ __forceinline__ float gelu_f(float v) {
    return 0.5f * v * (1.f + erff(v * 0.70710678118654752f));
}

// ---------------------------------------------------------------------------
// LayerNorm (fp32 in, bf16 out); PERM=1 permutes token order -> window order
// ---------------------------------------------------------------------------
template<int PERM>
__global__ __launch_bounds__(64) void ln_kernel(
    const float* __restrict__ in, const float* __restrict__ g,
    const float* __restrict__ b, u16* __restrict__ out)
{
    int row  = blockIdx.x;
    int lane = threadIdx.x;
    const float* rp = in + (size_t)row * DIMC;
    float v[6];
#pragma unroll
    for (int i = 0; i < 6; ++i) v[i] = rp[lane + i * 64];
    float s = 0.f;
#pragma unroll
    for (int i = 0; i < 6; ++i) s += v[i];
#pragma unroll
    for (int off = 32; off >= 1; off >>= 1) s += __shfl_down(s, off);
    float mu = __shfl(s, 0) * (1.f / 384.f);
    float q = 0.f;
#pragma unroll
    for (int i = 0; i < 6; ++i) { float d = v[i] - mu; q += d * d; }
#pragma unroll
    for (int off = 32; off >= 1; off >>= 1) q += __shfl_down(q, off);
    float rstd = rsqrtf(__shfl(q, 0) * (1.f / 384.f) + 1e-5f);

    size_t ob;
    if (PERM) {
        int bb = row >> 14;
        int t  = row & 16383;
        int hh = t >> 9;
        int ww = (t >> 4) & 31;
        int ll = t & 15;
        int wi = ((hh >> 3) * 4 + (ww >> 3)) * 2 + (ll >> 3);
        int p  = (((hh & 7) * 8) + (ww & 7)) * 8 + (ll & 7);
        ob = ((size_t)((bb * 32 + wi) * NWINP + p)) * DIMC;
    } else {
        ob = (size_t)row * DIMC;
    }
#pragma unroll
    for (int i = 0; i < 6; ++i) {
        int c = lane + i * 64;
        out[ob + c] = f2bf((v[i] - mu) * rstd * g[c] + b[c]);
    }
}

// ---------------------------------------------------------------------------
// GEMM: C[.,N] = A[.,K](bf16) @ W[N,K](fp32)^T + bias(f32)
// EPI: 0 = bf16 store, 1 = GELU bf16 store,
//      2 = window_reverse + shortcut add (fp32 out), 3 = fp32 accumulate
// 64x64x16 tile, 256 threads, 4x4/thread, k-major fp32 LDS.
// ---------------------------------------------------------------------------
constexpr int BM = 64, BN = 64, BK = 16;

template<int EPI>
__global__ __launch_bounds__(256) void gemm_bf16(
    const u16* __restrict__ A, const float* __restrict__ W,
    const float* __restrict__ bias, void* __restrict__ Cv,
    int K, int ldc, const float* __restrict__ extra)
{
    __shared__ float As[BK][BM + 4];
    __shared__ float Ws[BK][BN + 4];
    int tid = threadIdx.x;
    int tx = tid & 15, ty = tid >> 4;
    int bm = blockIdx.y * BM, bn = blockIdx.x * BN;

    int lrow = (tid >> 1) & 63;
    int kseg = (tid & 1) * 8;
    const u16*   srcA = A + (size_t)(bm + lrow) * K;
    const float* srcW = W + (size_t)(bn + lrow) * K;

    float acc[4][4];
#pragma unroll
    for (int i = 0; i < 4; ++i)
#pragma unroll
        for (int j = 0; j < 4; ++j) acc[i][j] = 0.f;

    for (int k0 = 0; k0 < K; k0 += BK) {
        if (tid < 128) {
            union { uint4 u; u16 s[8]; } uu;
            uu.u = *reinterpret_cast<const uint4*>(srcA + k0 + kseg);
#pragma unroll
            for (int j = 0; j < 8; ++j) As[kseg + j][lrow] = bf2f(uu.s[j]);
        } else {
            float4 w0 = *reinterpret_cast<const float4*>(srcW + k0 + kseg);
            float4 w1 = *reinterpret_cast<const float4*>(srcW + k0 + kseg + 4);
            Ws[kseg + 0][lrow] = w0.x; Ws[kseg + 1][lrow] = w0.y;
            Ws[kseg + 2][lrow] = w0.z; Ws[kseg + 3][lrow] = w0.w;
            Ws[kseg + 4][lrow] = w1.x; Ws[kseg + 5][lrow] = w1.y;
            Ws[kseg + 6][lrow] = w1.z; Ws[kseg + 7][lrow] = w1.w;
        }
        __syncthreads();
#pragma unroll
        for (int kk = 0; kk < BK; ++kk) {
            float4 rav = *reinterpret_cast<const float4*>(&As[kk][ty * 4]);
            float4 rwv = *reinterpret_cast<const float4*>(&Ws[kk][tx * 4]);
            float ra[4] = {rav.x, rav.y, rav.z, rav.w};
            float rw[4] = {rwv.x, rwv.y, rwv.z, rwv.w};
#pragma unroll
            for (int i = 0; i < 4; ++i)
#pragma unroll
                for (int j = 0; j < 4; ++j)
                    acc[i][j] = fmaf(ra[i], rw[j], acc[i][j]);
        }
        __syncthreads();
    }

#pragma unroll
    for (int i = 0; i < 4; ++i) {
        int row = bm + ty * 4 + i;
        size_t obase;
        if (EPI == 2) {
            int b_ = row >> 9, p = row & 511;
            int bbat = b_ >> 5, wi = b_ & 31;
            int hb = wi >> 3, rem = wi & 7, wb = rem >> 1, lb = rem & 1;
            int ih = p >> 6, iw = (p >> 3) & 7, il = p & 7;
            int t = ((hb * 8 + ih) * 32 + (wb * 8 + iw)) * 16 + (lb * 8 + il);
            obase = ((size_t)bbat * 16384 + t) * DIMC;
        } else {
            obase = (size_t)row * ldc;
        }
#pragma unroll
        for (int j = 0; j < 4; ++j) {
            int col = bn + tx * 4 + j;
            float v = acc[i][j] + bias[col];
            if (EPI == 0)      ((u16*)Cv)[obase + col] = f2bf(v);
            else if (EPI == 1) ((u16*)Cv)[obase + col] = f2bf(gelu_f(v));
            else if (EPI == 2) ((float*)Cv)[obase + col] = extra[obase + col] + v;
            else               ((float*)Cv)[obase + col] += v;
        }
    }
}

// ---------------------------------------------------------------------------
// PoLA attention core: one block per (window b_, head h). N=512, HD=32.
// qkv rows (bf16): [k(384) v(384) g(384)]; qb (bf16) in window order.
// Writes xo (fp32, proper [n][h*32+d] layout) into d_out scratch.
// ---------------------------------------------------------------------------
__global__ __launch_bounds__(256) void attn_kernel(
    const u16* __restrict__ qkv, const u16* __restrict__ qb,
    const float* __restrict__ pos_enc, const float* __restrict__ scale_p,
    const float* __restrict__ power_p, float* __restrict__ xo)
{
    int b_ = blockIdx.x / HEADS;
    int h  = blockIdx.x % HEADS;
    int tid = threadIdx.x;

    __shared__ float kc_s[64][64];   // kc chunk; reused for qf
    __shared__ float v_s[64][HD];
    __shared__ float kv_s[64][HD];
    __shared__ float km_s[64];
    __shared__ float z_s[64][2];
    __shared__ float isc_s[HD], pw_s[HD];

    if (tid < HD) {
        float sp = scale_p[h * HD + tid];
        float spv = (sp > 20.f) ? sp : log1pf(expf(sp));
        isc_s[tid] = 1.f / spv;
        float pp = power_p[h * HD + tid];
        pw_s[tid] = 1.f + 4.f / (1.f + expf(-pp));
    }
    __syncthreads();

    int lane = tid & 63;
    int w    = tid >> 6;
    const int cbase = h * HD;

    float acc[8];
#pragma unroll
    for (int j = 0; j < 8; ++j) acc[j] = 0.f;
    float kmsum = 0.f;

    for (int c8 = 0; c8 < 8; ++c8) {
        int n0 = c8 * 64;
#pragma unroll
        for (int i = 0; i < 8; ++i) {
            int idx = tid + i * 256;
            int nl = idx >> 5, d = idx & 31;
            size_t t = (size_t)(b_ * 512 + n0 + nl);
            float kraw = bf2f(qkv[t * QKVW + cbase + d])
                       + pos_enc[(size_t)(n0 + nl) * DIMC + cbase + d];
            float kk = kraw * isc_s[d];
            float p  = pw_s[d];
            kc_s[nl][d]      = relu_pow_f(kk, p);
            kc_s[nl][HD + d] = relu_pow_f(-kk, p);
            v_s[nl][d] = bf2f(qkv[t * QKVW + 384 + cbase + d]);
        }
        __syncthreads();
        int dvb = w * 8;
        for (int n = 0; n < 64; ++n) {
            float kcv = kc_s[n][lane];
            if (w == 0) kmsum += kcv;
            const float4* vr = reinterpret_cast<const float4*>(&v_s[n][dvb]);
            float4 v0 = vr[0], v1 = vr[1];
            acc[0] += kcv * v0.x; acc[1] += kcv * v0.y;
            acc[2] += kcv * v0.z; acc[3] += kcv * v0.w;
            acc[4] += kcv * v1.x; acc[5] += kcv * v1.y;
            acc[6] += kcv * v1.z; acc[7] += kcv * v1.w;
        }
        __syncthreads();
    }
#pragma unroll
    for (int j = 0; j < 8; ++j) kv_s[lane][w * 8 + j] = acc[j] * (1.f / 512.f);
    if (w == 0) km_s[lane] = kmsum * (1.f / 512.f);
    __syncthreads();

    float* qf_s = &kc_s[0][0];
    for (int c8 = 0; c8 < 8; ++c8) {
        int n0 = c8 * 64;
#pragma unroll
        for (int i = 0; i < 8; ++i) {
            int idx = tid + i * 256;
            int nl = idx >> 5, d = idx & 31;
            size_t t = (size_t)(b_ * 512 + n0 + nl);
            float qv = bf2f(qb[t * DIMC + cbase + d]) * isc_s[d];
            float p  = pw_s[d];
            qf_s[nl * 64 + d]      = relu_pow_f(qv, p);
            qf_s[nl * 64 + HD + d] = relu_pow_f(-qv, p);
        }
        __syncthreads();
        if (tid < 128) {
            int nl = tid >> 1, xorm = (tid & 1) * 32;
            float s = 0.f;
            for (int ff = 0; ff < 64; ++ff)
                s += qf_s[nl * 64 + (ff ^ xorm)] * km_s[ff];
            z_s[nl][tid & 1] = 1.f / (s + 1e-6f);
        }
        __syncthreads();
        {
            int d  = tid & 31;
            int nb = (tid >> 5) * 8;
            int xorm = (d < 16) ? 0 : 32;   // q_opp[f] == q_sim[f^32]
            int zi   = (d < 16) ? 0 : 1;
#pragma unroll
            for (int ni = 0; ni < 8; ++ni) {
                int nl = nb + ni;
                const float* qrow = qf_s + nl * 64;
                float s = 0.f;
                for (int ff = 0; ff < 64; ++ff)
                    s += qrow[ff ^ xorm] * kv_s[ff][d];
                size_t t = (size_t)(b_ * 512 + n0 + nl);
                xo[t * DIMC + cbase + d] = s * z_s[nl][zi];
            }
        }
        __syncthreads();
    }
}

// ---------------------------------------------------------------------------
// Depthwise 5x5x5 conv (SAME) on v, per (window, head); fused (xo+vv)*g.
// OUTPUT LOCATION IS THE REFERENCE'S SCRAMBLED RESHAPE:
//   (h, n, ch) -> flat = h*16384 + n*32 + ch; n' = flat/384; c' = flat%384.
// ---------------------------------------------------------------------------
__global__ __launch_bounds__(256) void dwconv_kernel(
    const u16* __restrict__ qkv, const float* __restrict__ xo,
    const float* __restrict__ dwc_w, const float* __restrict__ dwc_b,
    u16* __restrict__ outp)
{
    int b_ = blockIdx.x / HEADS;
    int h  = blockIdx.x % HEADS;
    int tid = threadIdx.x;
    __shared__ float v_s[512][HD];     // 64 KB
    __shared__ float w_s[125][HD];     // 15.6 KB

    for (int i = tid; i < 512 * HD; i += 256) {
        int n = i >> 5, ch = i & 31;
        v_s[n][ch] = bf2f(qkv[(size_t)(b_ * 512 + n) * QKVW + 384 + h * HD + ch]);
    }
    for (int i = tid; i < 125 * HD; i += 256)
        (&w_s[0][0])[i] = dwc_w[i];
    __syncthreads();

    for (int i = 0; i < 8; ++i) {
        int idx = tid + i * 256;
        int ch = idx & 31;
        int zy = idx >> 5;
        int z = zy >> 3, yy = zy & 7;
        float bias = dwc_b[ch];
        float acc[8];
#pragma unroll
        for (int xx = 0; xx < 8; ++xx) acc[xx] = bias;

        int kd0 = max(0, 2 - z),  kd1 = min(5, 10 - z);
        int kh0 = max(0, 2 - yy), kh1 = min(5, 10 - yy);
        for (int kd = kd0; kd < kd1; ++kd) {
            int zi = z + kd - 2;
            for (int kh = kh0; kh < kh1; ++kh) {
                int yi = yy + kh - 2;
                const float* vr = &v_s[(zi << 6) + (yi << 3)][ch];
                float vv[8];
#pragma unroll
                for (int xx = 0; xx < 8; ++xx) vv[xx] = vr[xx * HD];
                const float* wr = &w_s[(kd * 5 + kh) * 5][ch];
#pragma unroll
                for (int kw = 0; kw < 5; ++kw) {
                    float wv = wr[kw * HD];
#pragma unroll
                    for (int xx = 0; xx < 8; ++xx) {
                        int xi = xx + kw - 2;
                        if (xi >= 0 && xi < 8) acc[xx] += vv[xi] * wv;
                    }
                }
            }
        }
#pragma unroll
        for (int xx = 0; xx < 8; ++xx) {
            int n = (zy << 3) + xx;
            // reference's scrambled reshape destination:
            int flat = h * 16384 + n * 32 + ch;
            int nprime = flat / 384;
            int cprime = flat - nprime * 384;
            size_t tprime = (size_t)(b_ * 512 + nprime);
            size_t oi = tprime * DIMC + cprime;
            float gg = bf2f(qkv[tprime * QKVW + 768 + cprime]);
            outp[oi] = f2bf((xo[oi] + acc[xx]) * gg);
        }
    }
}

// ---------------------------------------------------------------------------
// Orchestration
// ---------------------------------------------------------------------------
extern "C" void kernel_launch(void* const* d_in, const int* in_sizes, int n_in,
                              void* d_out, int out_size, void* d_ws, size_t ws_size,
                              hipStream_t stream) {
    const float* x       = (const float*)d_in[0];
    const float* y       = (const float*)d_in[1];
    const float* w_qkvg  = (const float*)d_in[2];
    const float* b_qkvg  = (const float*)d_in[3];
    const float* w_proj  = (const float*)d_in[4];
    const float* b_proj  = (const float*)d_in[5];
    const float* dwc_w   = (const float*)d_in[6];
    const float* dwc_b   = (const float*)d_in[7];
    const float* power_p = (const float*)d_in[8];
    const float* scale_p = (const float*)d_in[9];
    const float* pos_enc = (const float*)d_in[10];
    const float* g1      = (const float*)d_in[11];
    const float* b1      = (const float*)d_in[12];
    const float* g2      = (const float*)d_in[13];
    const float* b2      = (const float*)d_in[14];
    const float* w_fc1   = (const float*)d_in[15];
    const float* b_fc1   = (const float*)d_in[16];
    const float* w_fc2   = (const float*)d_in[17];
    const float* b_fc2   = (const float*)d_in[18];
    float* out = (float*)d_out;

    const size_t M = TOT;
    // Workspace (u16 units), total M*1920*2 = 125.8 MB:
    //   P0 = M*384  : xw -> q -> ln2out
    //   P2 = M*1152 : qkv(k,v,g)
    //   P1 = M*384  : yw -> conv_out -> h1 chunk (8192*1536, exact fit)
    // xo (fp32, M*384) lives in d_out (overwritten by proj epilogue).
    u16* P0 = (u16*)d_ws;
    u16* P2 = P0 + M * 384;
    u16* P1 = P2 + M * 1152;

    // 1) LN + window partition
    ln_kernel<1><<<TOT, 64, 0, stream>>>(x, g1, b1, P0);
    ln_kernel<1><<<TOT, 64, 0, stream>>>(y, g1, b1, P1);
    // 2) qkv (k,v,g) from xw; then q from yw (q overwrites... no, q -> P0
    //    AFTER qkv consumed P0? No: qkv reads P0, writes P2; q reads P1,
    //    writes P0 — stream order serializes, and q GEMM may not overwrite
    //    P0 until qkv GEMM finished (separate dispatches, in-order stream).
    gemm_bf16<0><<<dim3(QKVW / BN, M / BM), 256, 0, stream>>>(
        P0, w_qkvg + 384 * 384, b_qkvg + 384, P2, 384, QKVW, nullptr);
    gemm_bf16<0><<<dim3(384 / BN, M / BM), 256, 0, stream>>>(
        P1, w_qkvg, b_qkvg, P0, 384, 384, nullptr);
    // 3) attention core -> xo in d_out (scratch)
    attn_kernel<<<64 * HEADS, 256, 0, stream>>>(P2, P0, pos_enc, scale_p, power_p, out);
    // 4) depthwise conv + scrambled (xo+vv)*g -> P1
    dwconv_kernel<<<64 * HEADS, 256, 0, stream>>>(P2, out, dwc_w, dwc_b, P1);
    // 5) proj + window reverse + shortcut -> out = x2
    gemm_bf16<2><<<dim3(384 / BN, M / BM), 256, 0, stream>>>(
        P1, w_proj, b_proj, out, 384, 384, x);
    // 6) LN2 -> P0
    ln_kernel<0><<<TOT, 64, 0, stream>>>(out, g2, b2, P0);
    // 7/8) fc1+GELU, fc2 accumulate — chunked over M in 4 slices of 8192 rows
    for (int c = 0; c < 4; ++c) {
        size_t off = (size_t)c * 8192;
        gemm_bf16<1><<<dim3(1536 / BN, 8192 / BM), 256, 0, stream>>>(
            P0 + off * 384, w_fc1, b_fc1, P1, 384, 1536, nullptr);
        gemm_bf16<3><<<dim3(384 / BN, 8192 / BM), 256, 0, stream>>>(
            P1, w_fc2, b_fc2, out + off * 384, 1536, 384, nullptr);
    }
}

// Round 4
// 964.344 us; speedup vs baseline: 2.3436x; 2.3436x over previous
//
#include <hip/hip_runtime.h>
#include <cstddef>
#include <cstdint>

// ---------------------------------------------------------------------------
// SwinTransformerBlock (PoLA attention), B=2, RES=(32,32,16), WS=(8,8,8)
// fp32 in/out; bf16 activations in workspace; fp32 weights converted to bf16
// during GEMM staging. GEMMs use v_mfma_f32_16x16x32_bf16 (gemm_bt pattern).
// NOTE: the reference's  vv.reshape(B_, N, C)  after the depthwise conv is a
// channel SCRAMBLE (no head transpose!): (h,n,d) -> flat = h*16384+n*32+d ->
// (n', c') = (flat/384, flat%384). We replicate that exactly.
// ---------------------------------------------------------------------------
constexpr int DIMC  = 384;
constexpr int HEADS = 12;
constexpr int HD    = 32;
constexpr int NWINP = 512;
constexpr int TOT   = 32768;   // B * 32*32*16
constexpr int QKVW  = 1152;    // k,v,g only (3*384)

using u16 = unsigned short;
using f32x4  = __attribute__((ext_vector_type(4))) float;
using bf16x8 = __attribute__((ext_vector_type(8))) short;

__device__ __forceinline__ float bf2f(u16 u) {
    union { uint32_t i; float f; } c; c.i = ((uint32_t)u) << 16; return c.f;
}
__device__ __forceinline__ u16 f2bf(float f) {
    union { float f; uint32_t i; } c; c.f = f;
    uint32_t r = c.i + 0x7fffu + ((c.i >> 16) & 1u);
    return (u16)(r >> 16);
}
__device__ __forceinline__ uint4 pack_bf16x8(float4 a, float4 b) {
    union { uint4 v; u16 s[8]; } r;
    r.s[0] = f2bf(a.x); r.s[1] = f2bf(a.y); r.s[2] = f2bf(a.z); r.s[3] = f2bf(a.w);
    r.s[4] = f2bf(b.x); r.s[5] = f2bf(b.y); r.s[6] = f2bf(b.z); r.s[7] = f2bf(b.w);
    return r.v;
}
__device__ __forceinline__ float relu_pow_f(float x, float p) {
    return (x > 0.f) ? __expf(p * __logf(x)) : 0.f;
}
__device__ __forceinline__ float gelu_f(float v) {
    return 0.5f * v * (1.f + erff(v * 0.70710678118654752f));
}

// ---------------------------------------------------------------------------
// LayerNorm (fp32 in, bf16 out); PERM=1 permutes token order -> window order
// ---------------------------------------------------------------------------
template<int PERM>
__global__ __launch_bounds__(64) void ln_kernel(
    const float* __restrict__ in, const float* __restrict__ g,
    const float* __restrict__ b, u16* __restrict__ out)
{
    int row  = blockIdx.x;
    int lane = threadIdx.x;
    const float* rp = in + (size_t)row * DIMC;
    float v[6];
#pragma unroll
    for (int i = 0; i < 6; ++i) v[i] = rp[lane + i * 64];
    float s = 0.f;
#pragma unroll
    for (int i = 0; i < 6; ++i) s += v[i];
#pragma unroll
    for (int off = 32; off >= 1; off >>= 1) s += __shfl_down(s, off);
    float mu = __shfl(s, 0) * (1.f / 384.f);
    float q = 0.f;
#pragma unroll
    for (int i = 0; i < 6; ++i) { float d = v[i] - mu; q += d * d; }
#pragma unroll
    for (int off = 32; off >= 1; off >>= 1) q += __shfl_down(q, off);
    float rstd = rsqrtf(__shfl(q, 0) * (1.f / 384.f) + 1e-5f);

    size_t ob;
    if (PERM) {
        int bb = row >> 14;
        int t  = row & 16383;
        int hh = t >> 9;
        int ww = (t >> 4) & 31;
        int ll = t & 15;
        int wi = ((hh >> 3) * 4 + (ww >> 3)) * 2 + (ll >> 3);
        int p  = (((hh & 7) * 8) + (ww & 7)) * 8 + (ll & 7);
        ob = ((size_t)((bb * 32 + wi) * NWINP + p)) * DIMC;
    } else {
        ob = (size_t)row * DIMC;
    }
#pragma unroll
    for (int i = 0; i < 6; ++i) {
        int c = lane + i * 64;
        out[ob + c] = f2bf((v[i] - mu) * rstd * g[c] + b[c]);
    }
}

// ---------------------------------------------------------------------------
// MFMA GEMM: C[.,N] = A[.,K](bf16) @ W[N,K](fp32->bf16)^T + bias(f32)
// 128x128 tile, 4 waves (each 64x64), BK=32, v_mfma_f32_16x16x32_bf16.
// EPI: 0 = bf16 store, 1 = GELU bf16 store,
//      2 = window_reverse + shortcut add (fp32 out), 3 = fp32 accumulate
// ---------------------------------------------------------------------------
template<int EPI>
__global__ __launch_bounds__(256) void gemm_mfma(
    const u16* __restrict__ A, const float* __restrict__ W,
    const float* __restrict__ bias, void* __restrict__ Cv,
    int K, int ldc, const float* __restrict__ extra)
{
    __shared__ u16 Asm[128 * 32];
    __shared__ u16 Bsm[128 * 32];
    int tid  = threadIdx.x;
    int lane = tid & 63, wid = tid >> 6;
    int wr = wid >> 1, wc = wid & 1;
    int bm = blockIdx.y * 128, bn = blockIdx.x * 128;

    // staging: thread t covers (row = t>>2 [+64], 8-elem k-seg = (t&3)*8)
    int srow = tid >> 2;
    int sseg = (tid & 3) * 8;
    const u16*   aS0 = A + (size_t)(bm + srow) * K + sseg;
    const u16*   aS1 = A + (size_t)(bm + 64 + srow) * K + sseg;
    const float* wS0 = W + (size_t)(bn + srow) * K + sseg;
    const float* wS1 = W + (size_t)(bn + 64 + srow) * K + sseg;
    u16* aD0 = &Asm[srow * 32 + sseg];
    u16* aD1 = &Asm[(64 + srow) * 32 + sseg];
    u16* bD0 = &Bsm[srow * 32 + sseg];
    u16* bD1 = &Bsm[(64 + srow) * 32 + sseg];

    f32x4 acc[4][4] = {};

    int frow = lane & 15;           // fragment row (A) / col (B)
    int fk   = (lane >> 4) * 8;     // k-group

    for (int k0 = 0; k0 < K; k0 += 32) {
        uint4 a0 = *reinterpret_cast<const uint4*>(aS0 + k0);
        uint4 a1 = *reinterpret_cast<const uint4*>(aS1 + k0);
        float4 w00 = *reinterpret_cast<const float4*>(wS0 + k0);
        float4 w01 = *reinterpret_cast<const float4*>(wS0 + k0 + 4);
        float4 w10 = *reinterpret_cast<const float4*>(wS1 + k0);
        float4 w11 = *reinterpret_cast<const float4*>(wS1 + k0 + 4);
        uint4 b0 = pack_bf16x8(w00, w01);
        uint4 b1 = pack_bf16x8(w10, w11);
        __syncthreads();   // previous iter's LDS reads done
        *reinterpret_cast<uint4*>(aD0) = a0;
        *reinterpret_cast<uint4*>(aD1) = a1;
        *reinterpret_cast<uint4*>(bD0) = b0;
        *reinterpret_cast<uint4*>(bD1) = b1;
        __syncthreads();

        bf16x8 af[4], bfr[4];
#pragma unroll
        for (int m = 0; m < 4; ++m)
            af[m] = *reinterpret_cast<const bf16x8*>(
                &Asm[(wr * 64 + m * 16 + frow) * 32 + fk]);
#pragma unroll
        for (int n = 0; n < 4; ++n)
            bfr[n] = *reinterpret_cast<const bf16x8*>(
                &Bsm[(wc * 64 + n * 16 + frow) * 32 + fk]);
#pragma unroll
        for (int m = 0; m < 4; ++m)
#pragma unroll
            for (int n = 0; n < 4; ++n)
                acc[m][n] = __builtin_amdgcn_mfma_f32_16x16x32_bf16(
                    af[m], bfr[n], acc[m][n], 0, 0, 0);
    }

    // epilogue: C/D layout col=lane&15, row=(lane>>4)*4+reg
#pragma unroll
    for (int m = 0; m < 4; ++m) {
#pragma unroll
        for (int r = 0; r < 4; ++r) {
            int row = bm + wr * 64 + m * 16 + (lane >> 4) * 4 + r;
            size_t obase;
            if (EPI == 2) {
                int b_ = row >> 9, p = row & 511;
                int bbat = b_ >> 5, wi = b_ & 31;
                int hb = wi >> 3, rem = wi & 7, wb = rem >> 1, lb = rem & 1;
                int ih = p >> 6, iw = (p >> 3) & 7, il = p & 7;
                int t = ((hb * 8 + ih) * 32 + (wb * 8 + iw)) * 16 + (lb * 8 + il);
                obase = ((size_t)bbat * 16384 + t) * DIMC;
            } else {
                obase = (size_t)row * ldc;
            }
#pragma unroll
            for (int n = 0; n < 4; ++n) {
                int col = bn + wc * 64 + n * 16 + (lane & 15);
                float v = acc[m][n][r] + bias[col];
                if (EPI == 0)      ((u16*)Cv)[obase + col] = f2bf(v);
                else if (EPI == 1) ((u16*)Cv)[obase + col] = f2bf(gelu_f(v));
                else if (EPI == 2) ((float*)Cv)[obase + col] = extra[obase + col] + v;
                else               ((float*)Cv)[obase + col] += v;
            }
        }
    }
}

// ---------------------------------------------------------------------------
// PoLA attention core: one block per (window b_, head h). N=512, HD=32.
// qkv rows (bf16): [k(384) v(384) g(384)]; qb (bf16) in window order.
// Writes xo (fp32, proper [n][h*32+d] layout) into d_out scratch.
// ---------------------------------------------------------------------------
__global__ __launch_bounds__(256) void attn_kernel(
    const u16* __restrict__ qkv, const u16* __restrict__ qb,
    const float* __restrict__ pos_enc, const float* __restrict__ scale_p,
    const float* __restrict__ power_p, float* __restrict__ xo)
{
    int b_ = blockIdx.x / HEADS;
    int h  = blockIdx.x % HEADS;
    int tid = threadIdx.x;

    __shared__ float kc_s[64][64];   // kc chunk; reused for qf
    __shared__ float v_s[64][HD];
    __shared__ float kv_s[64][HD];
    __shared__ float km_s[64];
    __shared__ float z_s[64][2];
    __shared__ float isc_s[HD], pw_s[HD];

    if (tid < HD) {
        float sp = scale_p[h * HD + tid];
        float spv = (sp > 20.f) ? sp : log1pf(expf(sp));
        isc_s[tid] = 1.f / spv;
        float pp = power_p[h * HD + tid];
        pw_s[tid] = 1.f + 4.f / (1.f + expf(-pp));
    }
    __syncthreads();

    int lane = tid & 63;
    int w    = tid >> 6;
    const int cbase = h * HD;

    float acc[8];
#pragma unroll
    for (int j = 0; j < 8; ++j) acc[j] = 0.f;
    float kmsum = 0.f;

    for (int c8 = 0; c8 < 8; ++c8) {
        int n0 = c8 * 64;
#pragma unroll
        for (int i = 0; i < 8; ++i) {
            int idx = tid + i * 256;
            int nl = idx >> 5, d = idx & 31;
            size_t t = (size_t)(b_ * 512 + n0 + nl);
            float kraw = bf2f(qkv[t * QKVW + cbase + d])
                       + pos_enc[(size_t)(n0 + nl) * DIMC + cbase + d];
            float kk = kraw * isc_s[d];
            float p  = pw_s[d];
            kc_s[nl][d]      = relu_pow_f(kk, p);
            kc_s[nl][HD + d] = relu_pow_f(-kk, p);
            v_s[nl][d] = bf2f(qkv[t * QKVW + 384 + cbase + d]);
        }
        __syncthreads();
        int dvb = w * 8;
        for (int n = 0; n < 64; ++n) {
            float kcv = kc_s[n][lane];
            if (w == 0) kmsum += kcv;
            const float4* vr = reinterpret_cast<const float4*>(&v_s[n][dvb]);
            float4 v0 = vr[0], v1 = vr[1];
            acc[0] += kcv * v0.x; acc[1] += kcv * v0.y;
            acc[2] += kcv * v0.z; acc[3] += kcv * v0.w;
            acc[4] += kcv * v1.x; acc[5] += kcv * v1.y;
            acc[6] += kcv * v1.z; acc[7] += kcv * v1.w;
        }
        __syncthreads();
    }
#pragma unroll
    for (int j = 0; j < 8; ++j) kv_s[lane][w * 8 + j] = acc[j] * (1.f / 512.f);
    if (w == 0) km_s[lane] = kmsum * (1.f / 512.f);
    __syncthreads();

    float* qf_s = &kc_s[0][0];
    for (int c8 = 0; c8 < 8; ++c8) {
        int n0 = c8 * 64;
#pragma unroll
        for (int i = 0; i < 8; ++i) {
            int idx = tid + i * 256;
            int nl = idx >> 5, d = idx & 31;
            size_t t = (size_t)(b_ * 512 + n0 + nl);
            float qv = bf2f(qb[t * DIMC + cbase + d]) * isc_s[d];
            float p  = pw_s[d];
            qf_s[nl * 64 + d]      = relu_pow_f(qv, p);
            qf_s[nl * 64 + HD + d] = relu_pow_f(-qv, p);
        }
        __syncthreads();
        if (tid < 128) {
            int nl = tid >> 1, xorm = (tid & 1) * 32;
            float s = 0.f;
            for (int ff = 0; ff < 64; ++ff)
                s += qf_s[nl * 64 + (ff ^ xorm)] * km_s[ff];
            z_s[nl][tid & 1] = 1.f / (s + 1e-6f);
        }
        __syncthreads();
        {
            int d  = tid & 31;
            int nb = (tid >> 5) * 8;
            int xorm = (d < 16) ? 0 : 32;   // q_opp[f] == q_sim[f^32]
            int zi   = (d < 16) ? 0 : 1;
#pragma unroll
            for (int ni = 0; ni < 8; ++ni) {
                int nl = nb + ni;
                const float* qrow = qf_s + nl * 64;
                float s = 0.f;
                for (int ff = 0; ff < 64; ++ff)
                    s += qrow[ff ^ xorm] * kv_s[ff][d];
                size_t t = (size_t)(b_ * 512 + n0 + nl);
                xo[t * DIMC + cbase + d] = s * z_s[nl][zi];
            }
        }
        __syncthreads();
    }
}

// ---------------------------------------------------------------------------
// Depthwise 5x5x5 conv (SAME) on v, per (window, head); fused (xo+vv)*g.
// OUTPUT LOCATION IS THE REFERENCE'S SCRAMBLED RESHAPE:
//   (h, n, ch) -> flat = h*16384 + n*32 + ch; n' = flat/384; c' = flat%384.
// ---------------------------------------------------------------------------
__global__ __launch_bounds__(256) void dwconv_kernel(
    const u16* __restrict__ qkv, const float* __restrict__ xo,
    const float* __restrict__ dwc_w, const float* __restrict__ dwc_b,
    u16* __restrict__ outp)
{
    int b_ = blockIdx.x / HEADS;
    int h  = blockIdx.x % HEADS;
    int tid = threadIdx.x;
    __shared__ float v_s[512][HD];     // 64 KB
    __shared__ float w_s[125][HD];     // 15.6 KB

    for (int i = tid; i < 512 * HD; i += 256) {
        int n = i >> 5, ch = i & 31;
        v_s[n][ch] = bf2f(qkv[(size_t)(b_ * 512 + n) * QKVW + 384 + h * HD + ch]);
    }
    for (int i = tid; i < 125 * HD; i += 256)
        (&w_s[0][0])[i] = dwc_w[i];
    __syncthreads();

    for (int i = 0; i < 8; ++i) {
        int idx = tid + i * 256;
        int ch = idx & 31;
        int zy = idx >> 5;
        int z = zy >> 3, yy = zy & 7;
        float bias = dwc_b[ch];
        float acc[8];
#pragma unroll
        for (int xx = 0; xx < 8; ++xx) acc[xx] = bias;

        int kd0 = max(0, 2 - z),  kd1 = min(5, 10 - z);
        int kh0 = max(0, 2 - yy), kh1 = min(5, 10 - yy);
        for (int kd = kd0; kd < kd1; ++kd) {
            int zi = z + kd - 2;
            for (int kh = kh0; kh < kh1; ++kh) {
                int yi = yy + kh - 2;
                const float* vr = &v_s[(zi << 6) + (yi << 3)][ch];
                float vv[8];
#pragma unroll
                for (int xx = 0; xx < 8; ++xx) vv[xx] = vr[xx * HD];
                const float* wr = &w_s[(kd * 5 + kh) * 5][ch];
#pragma unroll
                for (int kw = 0; kw < 5; ++kw) {
                    float wv = wr[kw * HD];
#pragma unroll
                    for (int xx = 0; xx < 8; ++xx) {
                        int xi = xx + kw - 2;
                        if (xi >= 0 && xi < 8) acc[xx] += vv[xi] * wv;
                    }
                }
            }
        }
#pragma unroll
        for (int xx = 0; xx < 8; ++xx) {
            int n = (zy << 3) + xx;
            int flat = h * 16384 + n * 32 + ch;
            int nprime = flat / 384;
            int cprime = flat - nprime * 384;
            size_t tprime = (size_t)(b_ * 512 + nprime);
            size_t oi = tprime * DIMC + cprime;
            float gg = bf2f(qkv[tprime * QKVW + 768 + cprime]);
            outp[oi] = f2bf((xo[oi] + acc[xx]) * gg);
        }
    }
}

// ---------------------------------------------------------------------------
// Orchestration
// ---------------------------------------------------------------------------
extern "C" void kernel_launch(void* const* d_in, const int* in_sizes, int n_in,
                              void* d_out, int out_size, void* d_ws, size_t ws_size,
                              hipStream_t stream) {
    const float* x       = (const float*)d_in[0];
    const float* y       = (const float*)d_in[1];
    const float* w_qkvg  = (const float*)d_in[2];
    const float* b_qkvg  = (const float*)d_in[3];
    const float* w_proj  = (const float*)d_in[4];
    const float* b_proj  = (const float*)d_in[5];
    const float* dwc_w   = (const float*)d_in[6];
    const float* dwc_b   = (const float*)d_in[7];
    const float* power_p = (const float*)d_in[8];
    const float* scale_p = (const float*)d_in[9];
    const float* pos_enc = (const float*)d_in[10];
    const float* g1      = (const float*)d_in[11];
    const float* b1      = (const float*)d_in[12];
    const float* g2      = (const float*)d_in[13];
    const float* b2      = (const float*)d_in[14];
    const float* w_fc1   = (const float*)d_in[15];
    const float* b_fc1   = (const float*)d_in[16];
    const float* w_fc2   = (const float*)d_in[17];
    const float* b_fc2   = (const float*)d_in[18];
    float* out = (float*)d_out;

    const size_t M = TOT;
    // Workspace (u16 units), total M*1920*2 = 125.8 MB (proven safe):
    //   P0 = M*384  : xw -> q -> ln2out
    //   P2 = M*1152 : qkv(k,v,g)
    //   P1 = M*384  : yw -> conv_out -> h1 chunk (8192*1536, exact fit)
    // xo (fp32, M*384) lives in d_out (overwritten by proj epilogue).
    u16* P0 = (u16*)d_ws;
    u16* P2 = P0 + M * 384;
    u16* P1 = P2 + M * 1152;

    // 1) LN + window partition
    ln_kernel<1><<<TOT, 64, 0, stream>>>(x, g1, b1, P0);
    ln_kernel<1><<<TOT, 64, 0, stream>>>(y, g1, b1, P1);
    // 2) qkv (k,v,g) from xw -> P2; then q from yw -> P0
    gemm_mfma<0><<<dim3(QKVW / 128, M / 128), 256, 0, stream>>>(
        P0, w_qkvg + 384 * 384, b_qkvg + 384, P2, 384, QKVW, nullptr);
    gemm_mfma<0><<<dim3(384 / 128, M / 128), 256, 0, stream>>>(
        P1, w_qkvg, b_qkvg, P0, 384, 384, nullptr);
    // 3) attention core -> xo in d_out (scratch)
    attn_kernel<<<64 * HEADS, 256, 0, stream>>>(P2, P0, pos_enc, scale_p, power_p, out);
    // 4) depthwise conv + scrambled (xo+vv)*g -> P1
    dwconv_kernel<<<64 * HEADS, 256, 0, stream>>>(P2, out, dwc_w, dwc_b, P1);
    // 5) proj + window reverse + shortcut -> out = x2
    gemm_mfma<2><<<dim3(384 / 128, M / 128), 256, 0, stream>>>(
        P1, w_proj, b_proj, out, 384, 384, x);
    // 6) LN2 -> P0
    ln_kernel<0><<<TOT, 64, 0, stream>>>(out, g2, b2, P0);
    // 7/8) fc1+GELU, fc2 accumulate — chunked over M in 4 slices of 8192 rows
    for (int c = 0; c < 4; ++c) {
        size_t off = (size_t)c * 8192;
        gemm_mfma<1><<<dim3(1536 / 128, 8192 / 128), 256, 0, stream>>>(
            P0 + off * 384, w_fc1, b_fc1, P1, 384, 1536, nullptr);
        gemm_mfma<3><<<dim3(384 / 128, 8192 / 128), 256, 0, stream>>>(
            P1, w_fc2, b_fc2, out + off * 384, 1536, 384, nullptr);
    }
}